// Round 1
// 1255.887 us; speedup vs baseline: 1.0785x; 1.0785x over previous
//
#include <hip/hip_runtime.h>

#define N_TOK 65536
#define DIM 256
#define KCB 1024
#define NLVL 8
#define TPB 64                        // tokens per block (k_main)
#define ND_OUT (N_TOK * DIM)          // 16777216
#define IDX_OFF ND_OUT
#define SC_OFF (ND_OUT + N_TOK * NLVL) // 17301504
#define EPSV 1e-6f

typedef _Float16 half8 __attribute__((ext_vector_type(8)));
typedef float f32x4 __attribute__((ext_vector_type(4)));

__device__ __forceinline__ float wave_red(float v) {
    v += __shfl_xor(v, 32, 64);
    v += __shfl_xor(v, 16, 64);
    v += __shfl_xor(v, 8, 64);
    v += __shfl_xor(v, 4, 64);
    v += __shfl_xor(v, 2, 64);
    v += __shfl_xor(v, 1, 64);
    return v;
}

// order-preserving float->uint map (monotone increasing)
__device__ __forceinline__ unsigned int ordf(float d) {
    unsigned int u = __float_as_uint(d);
    return (u & 0x80000000u) ? ~u : (u ^ 0x80000000u);
}

// ---------------- B-fragment precompute (fp16 hi/lo RNE split, scaled) ----------------
// layout: frag F = (lvl*8 + s)*64 + ntg ; at F*128: [hi: 64 x half8][lo: 64 x half8]
// lane l holds C[code = ntg*16 + (l&15)][dim = s*32 + (l>>4)*8 + j] * 2^(lvl+5)
__global__ __launch_bounds__(256) void k_prep(const float* __restrict__ cbs,
                                              half8* __restrict__ ws_b) {
    const int lvl = blockIdx.x >> 6, ntg = blockIdx.x & 63;
    const int lane = threadIdx.x & 63, sg = threadIdx.x >> 6;
    const float sc = (float)(1 << (lvl + 5));
#pragma unroll
    for (int ss = 0; ss < 2; ++ss) {
        const int s = sg + ss * 4;
        const int code = ntg * 16 + (lane & 15);
        const int d0 = s * 32 + (lane >> 4) * 8;
        const float* p = cbs + ((size_t)(lvl * KCB + code)) * DIM + d0;
        const float4 va = *(const float4*)p;
        const float4 vb = *(const float4*)(p + 4);
        float f[8] = {va.x, va.y, va.z, va.w, vb.x, vb.y, vb.z, vb.w};
        half8 h, l;
#pragma unroll
        for (int j = 0; j < 8; ++j) {
            float fs = f[j] * sc;
            _Float16 hh = (_Float16)fs;          // RNE
            h[j] = hh;
            l[j] = (_Float16)(fs - (float)hh);   // RNE
        }
        const size_t base = ((size_t)((lvl * 8 + s) * 64 + ntg)) * 128;
        ws_b[base + lane] = h;
        ws_b[base + 64 + lane] = l;
    }
}

// ---------------- scaled c_sq + ws zeroing ----------------
__global__ __launch_bounds__(256) void k_csq(const float* __restrict__ cbs,
                                             float* __restrict__ csq_s,
                                             int* __restrict__ gcounts,
                                             float* __restrict__ gloss) {
    const int tid = threadIdx.x;
    const int wv = tid >> 6, lane = tid & 63;
    const int code = blockIdx.x * 4 + wv; // 0..8191 (lvl*1024 + k)
    const float4 v = *(const float4*)(cbs + (size_t)code * DIM + lane * 4);
    float s = v.x * v.x + v.y * v.y + v.z * v.z + v.w * v.w;
    s = wave_red(s);
    const int lvl = code >> 10;
    if (lane == 0) csq_s[code] = s * (float)(1 << (10 + lvl));
    if (blockIdx.x == 0) {
#pragma unroll
        for (int i = 0; i < 4; ++i) gcounts[tid + i * 256] = 0;
        if (tid == 0) *gloss = 0.f;
    }
}

// ---------------- fused RVQ main ----------------
// 512 threads = 8 waves; block owns 64 tokens (M=64, 4 m-tiles of 16);
// wave w covers codes [w*128, w*128+128) = 8 code-tiles of 16.
// A hi/lo fragments are built ONCE per level into shared LDS (was 8x duplicated
// per-wave VALU); all waves consume identical bit-exact fragments.
__global__ __launch_bounds__(512, 2) void k_main(const float* __restrict__ z,
                                                 const float* __restrict__ cbs,
                                                 const half8* __restrict__ ws_b,
                                                 const float* __restrict__ csq_s,
                                                 float* __restrict__ out,
                                                 int* __restrict__ gcounts,
                                                 float* __restrict__ gloss) {
    __shared__ __align__(16) float Rld[TPB * DIM];     // 64 KB, x32-scaled, col4 = k4 ^ (t&15)
    __shared__ __align__(16) half8 Afrag[4096];        // 64 KB: frag (s*4+m): [hi:64][lo:64]
    __shared__ unsigned long long keyBuf[8][TPB + 1];  // padded: kills 8-way bank conflict
    __shared__ int idxBuf[TPB * NLVL];                 // 2 KB
    __shared__ int hist[KCB];                          // 4 KB
    __shared__ float wpart[8];

    const int tid = threadIdx.x;
    const int lane = tid & 63, w = tid >> 6;
    const int l15 = lane & 15, qd = lane >> 4;
    const int t0 = blockIdx.x * TPB;

    // stage z -> Rld, pre-scaled by 32 (exact pow2), swizzled
#pragma unroll
    for (int i = 0; i < 8; ++i) {
        int fi = tid + i * 512;          // float4 index 0..4095
        int t = fi >> 6, k4 = fi & 63;
        float4 v = *(const float4*)(z + (size_t)(t0 + t) * DIM + k4 * 4);
        v.x *= 32.f; v.y *= 32.f; v.z *= 32.f; v.w *= 32.f;
        *(float4*)&Rld[t * DIM + ((k4 ^ (t & 15)) << 2)] = v;
    }
#pragma unroll
    for (int i = 0; i < 2; ++i) hist[tid + i * 512] = 0;
    float loss_acc = 0.f;

    // B prefetch chain: carried across nt, s, AND levels (frags contiguous in (lvl,s))
    const half8* pbw = ws_b + (size_t)(w * 8) * 128 + lane;
    half8 bh = pbw[0], bl = pbw[64];
    __syncthreads();

    for (int lvl = 0; lvl < NLVL; ++lvl) {
        // ---- shared A-fragment build (hi/lo RNE split, bit-identical to per-wave ver) ----
        // 2048 fragments-pairs: f = (s*4+m)*64 + ln; thread handles 4 of them.
#pragma unroll
        for (int i = 0; i < 4; ++i) {
            const int f = tid + i * 512;           // 0..2047
            const int sm = f >> 6, ln = f & 63;    // sm = s*4+m
            const int s = sm >> 2, m = sm & 3;
            const int e = ln & 15;
            const int row = (m * 16 + e) * DIM;
            const int k4 = s * 8 + ((ln >> 4) << 1);
            float4 va = *(const float4*)&Rld[row + ((k4 ^ e) << 2)];
            float4 vb = *(const float4*)&Rld[row + (((k4 + 1) ^ e) << 2)];
            float fv[8] = {va.x, va.y, va.z, va.w, vb.x, vb.y, vb.z, vb.w};
            half8 h, l;
#pragma unroll
            for (int j = 0; j < 8; ++j) {
                _Float16 hh = (_Float16)fv[j];     // RNE
                h[j] = hh;
                l[j] = (_Float16)(fv[j] - (float)hh);
            }
            Afrag[sm * 128 + ln] = h;
            Afrag[sm * 128 + 64 + ln] = l;
        }
        __syncthreads();

        float bd[16];
        int bi[16];
#pragma unroll
        for (int i = 0; i < 16; ++i) { bd[i] = 3.402823466e38f; bi[i] = 0; }

        f32x4 acc[8][4];
#pragma unroll
        for (int nt = 0; nt < 8; ++nt)
#pragma unroll
            for (int m = 0; m < 4; ++m) acc[nt][m] = (f32x4){0.f, 0.f, 0.f, 0.f};

#pragma unroll 1
        for (int s = 0; s < 8; ++s) {
            // ---- A fragments: straight conflict-free ds_read_b128, no VALU ----
            half8 Ah[4], Al[4];
#pragma unroll
            for (int m = 0; m < 4; ++m) {
                Ah[m] = Afrag[(s * 4 + m) * 128 + lane];
                Al[m] = Afrag[(s * 4 + m) * 128 + 64 + lane];
            }
            // ---- B stream (L2), software-pipelined, 16 MFMA per load pair ----
            const half8* pb = ws_b + (((size_t)(lvl * 8 + s)) * 64 + w * 8) * 128 + lane;
#pragma unroll
            for (int nt = 0; nt < 8; ++nt) {
                const int off = (nt < 7) ? (nt + 1) * 128 : 64 * 128; // next tile / next (s|lvl)
                half8 nbh = pb[off];
                half8 nbl = pb[off + 64];
#pragma unroll
                for (int m = 0; m < 4; ++m)
                    acc[nt][m] = __builtin_amdgcn_mfma_f32_16x16x32_f16(Ah[m], bh, acc[nt][m], 0, 0, 0);
#pragma unroll
                for (int m = 0; m < 4; ++m)
                    acc[nt][m] = __builtin_amdgcn_mfma_f32_16x16x32_f16(Al[m], bh, acc[nt][m], 0, 0, 0);
#pragma unroll
                for (int m = 0; m < 4; ++m)
                    acc[nt][m] = __builtin_amdgcn_mfma_f32_16x16x32_f16(Ah[m], bl, acc[nt][m], 0, 0, 0);
#pragma unroll
                for (int m = 0; m < 4; ++m)
                    acc[nt][m] = __builtin_amdgcn_mfma_f32_16x16x32_f16(Al[m], bl, acc[nt][m], 0, 0, 0);
                bh = nbh;
                bl = nbl;
            }
        }
        // ---- distances + running argmin (tie -> smaller index) ----
        {
            const float* csqp = csq_s + lvl * KCB + w * 128 + l15;
#pragma unroll
            for (int nt = 0; nt < 8; ++nt) {
                const float cs = csqp[nt * 16];
                const int code = w * 128 + nt * 16 + l15;
#pragma unroll
                for (int m = 0; m < 4; ++m)
#pragma unroll
                    for (int i = 0; i < 4; ++i) {
                        float d = fmaf(-2.f, acc[nt][m][i], cs);
                        if (d < bd[m * 4 + i]) { bd[m * 4 + i] = d; bi[m * 4 + i] = code; }
                    }
            }
        }
        // ---- argmin cross-lane reduce over the 16 code-lanes ----
        unsigned long long key[16];
#pragma unroll
        for (int i = 0; i < 16; ++i)
            key[i] = (((unsigned long long)ordf(bd[i])) << 10) | (unsigned long long)bi[i];
#pragma unroll
        for (int m = 1; m <= 8; m <<= 1)
#pragma unroll
            for (int i = 0; i < 16; ++i) {
                unsigned long long o = __shfl_xor(key[i], m, 64);
                if (o < key[i]) key[i] = o;
            }
        if (l15 == 0) {
#pragma unroll
            for (int m = 0; m < 4; ++m)
#pragma unroll
                for (int i = 0; i < 4; ++i)
                    keyBuf[w][m * 16 + qd * 4 + i] = key[m * 4 + i];
        }
        __syncthreads();
        // ---- cross-wave min: every wave reduces its own 8 tokens (no serial section) ----
        unsigned long long kk = keyBuf[lane & 7][w * 8 + (lane >> 3)];
        {
            unsigned long long o1 = __shfl_xor(kk, 1, 64); if (o1 < kk) kk = o1;
            unsigned long long o2 = __shfl_xor(kk, 2, 64); if (o2 < kk) kk = o2;
            unsigned long long o4 = __shfl_xor(kk, 4, 64); if (o4 < kk) kk = o4;
        }
        const int myidx = (int)(kk & 1023ull);       // best code for token w*8 + (lane>>3)
        if ((lane & 7) == 0) {
            const int tl = w * 8 + (lane >> 3);
            idxBuf[tl * NLVL + lvl] = myidx;
            atomicAdd(&hist[myidx], 1);
        }

        // ---- epilogue: rotation trick + residual update (round-1 exact math) ----
        const float* cb = cbs + (size_t)lvl * KCB * DIM;
        for (int s2 = 0; s2 < 8; ++s2) {
            const int tl = w * 8 + s2;
            const int idx = __shfl(myidx, s2 * 8, 64);
            const int e = tl & 15;
            float4 r4 = *(const float4*)&Rld[tl * DIM + ((lane ^ e) << 2)];
            r4.x *= 0.03125f; r4.y *= 0.03125f; r4.z *= 0.03125f; r4.w *= 0.03125f;
            float4 c4 = *(const float4*)(cb + (size_t)idx * DIM + lane * 4);
            float rr = r4.x * r4.x + r4.y * r4.y + r4.z * r4.z + r4.w * r4.w;
            float cc = c4.x * c4.x + c4.y * c4.y + c4.z * c4.z + c4.w * c4.w;
            float e0 = (c4.x - r4.x) * (c4.x - r4.x) + (c4.y - r4.y) * (c4.y - r4.y) +
                       (c4.z - r4.z) * (c4.z - r4.z) + (c4.w - r4.w) * (c4.w - r4.w);
            rr = wave_red(rr);
            cc = wave_red(cc);
            e0 = wave_red(e0);
            const float dx = fmaxf(sqrtf(rr), EPSV);
            const float dc = fmaxf(sqrtf(cc), EPSV);
            float4 u4 = make_float4(r4.x / dx, r4.y / dx, r4.z / dx, r4.w / dx);
            float4 q4 = make_float4(c4.x / dc, c4.y / dc, c4.z / dc, c4.w / dc);
            float4 w4 = make_float4(u4.x + q4.x, u4.y + q4.y, u4.z + q4.z, u4.w + q4.w);
            float ww = w4.x * w4.x + w4.y * w4.y + w4.z * w4.z + w4.w * w4.w;
            float xw = r4.x * w4.x + r4.y * w4.y + r4.z * w4.z + r4.w * w4.w;
            float xu = r4.x * u4.x + r4.y * u4.y + r4.z * u4.z + r4.w * u4.w;
            ww = wave_red(ww);
            xw = wave_red(xw);
            xu = wave_red(xu);
            const float dw = fmaxf(sqrtf(ww), EPSV);
            const float xwn = xw / dw;
            float4 wn = make_float4(w4.x / dw, w4.y / dw, w4.z / dw, w4.w / dw);
            float4 zst = make_float4(r4.x - 2.f * xwn * wn.x + 2.f * xu * q4.x,
                                     r4.y - 2.f * xwn * wn.y + 2.f * xu * q4.y,
                                     r4.z - 2.f * xwn * wn.z + 2.f * xu * q4.z,
                                     r4.w - 2.f * xwn * wn.w + 2.f * xu * q4.w);
            float4 rn = make_float4((r4.x - zst.x) * 32.f, (r4.y - zst.y) * 32.f,
                                    (r4.z - zst.z) * 32.f, (r4.w - zst.w) * 32.f);
            *(float4*)&Rld[tl * DIM + ((lane ^ e) << 2)] = rn;
            loss_acc += e0;
        }
        __syncthreads();
    }

    // ---- outputs: z_q = z + (sum_l c[idx_l] - z) ----
    for (int s2 = 0; s2 < 8; ++s2) {
        const int tl = w * 8 + s2;
        const size_t trow = t0 + tl;
        float4 z4 = *(const float4*)(z + trow * DIM + lane * 4);
        float4 qs = make_float4(0.f, 0.f, 0.f, 0.f);
#pragma unroll
        for (int lvl = 0; lvl < NLVL; ++lvl) {
            const int idx = idxBuf[tl * NLVL + lvl];
            float4 c4 = *(const float4*)(cbs + ((size_t)(lvl * KCB + idx)) * DIM + lane * 4);
            qs.x += c4.x; qs.y += c4.y; qs.z += c4.z; qs.w += c4.w;
        }
        float4 o = make_float4(z4.x + (qs.x - z4.x), z4.y + (qs.y - z4.y),
                               z4.z + (qs.z - z4.z), z4.w + (qs.w - z4.w));
        *(float4*)(out + trow * DIM + lane * 4) = o;
    }
    // indices as float, [N, 8]
    out[IDX_OFF + (size_t)(t0 + (tid >> 3)) * NLVL + (tid & 7)] = (float)idxBuf[tid];
    // histogram flush
#pragma unroll
    for (int i = 0; i < 2; ++i) {
        int b = tid + i * 512;
        int h = hist[b];
        if (h) atomicAdd(&gcounts[b], h);
    }
    // loss partial
    if (lane == 0) wpart[w] = loss_acc;
    __syncthreads();
    if (tid == 0) {
        float sum = 0.f;
#pragma unroll
        for (int i = 0; i < 8; ++i) sum += wpart[i];
        atomicAdd(gloss, sum);
    }
}

// ---------------- scalars: losses + perplexity ----------------
__global__ __launch_bounds__(256) void k_fin(const int* __restrict__ gcounts,
                                             const float* __restrict__ gloss,
                                             float* __restrict__ out) {
    __shared__ float part[4];
    const int tid = threadIdx.x, lane = tid & 63, wv = tid >> 6;
    float e = 0.f;
#pragma unroll
    for (int i = 0; i < 4; ++i) {
        float c = (float)gcounts[tid * 4 + i];
        float p = c * (1.f / 524288.f);
        if (p > 0.f) e += p * logf(p);
    }
    e = wave_red(e);
    if (lane == 0) part[wv] = e;
    __syncthreads();
    if (tid == 0) {
        float ent = -(part[0] + part[1] + part[2] + part[3]);
        float cbl = *gloss * (1.f / 16777216.f);
        out[SC_OFF + 0] = cbl + 0.25f * cbl;
        out[SC_OFF + 1] = cbl;
        out[SC_OFF + 2] = cbl;
        out[SC_OFF + 3] = expf(ent);
    }
}

extern "C" void kernel_launch(void* const* d_in, const int* in_sizes, int n_in,
                              void* d_out, int out_size, void* d_ws, size_t ws_size,
                              hipStream_t stream) {
    (void)in_sizes; (void)n_in; (void)out_size; (void)ws_size;
    const float* z = (const float*)d_in[0];
    const float* cbs = (const float*)d_in[1];
    float* out = (float*)d_out;
    half8* ws_b = (half8*)d_ws;                                    // 8 MB fragments
    float* csq = (float*)((char*)d_ws + (8u << 20));               // 32 KB
    int* gcounts = (int*)((char*)d_ws + (8u << 20) + 32768);       // 4 KB
    float* gloss = (float*)((char*)d_ws + (8u << 20) + 32768 + 4096);

    hipLaunchKernelGGL(k_prep, dim3(512), dim3(256), 0, stream, cbs, ws_b);
    hipLaunchKernelGGL(k_csq, dim3(2048), dim3(256), 0, stream, cbs, csq, gcounts, gloss);
    hipLaunchKernelGGL(k_main, dim3(1024), dim3(512), 0, stream, z, cbs, ws_b, csq, out,
                       gcounts, gloss);
    hipLaunchKernelGGL(k_fin, dim3(1), dim3(256), 0, stream, gcounts, gloss, out);
}